// Round 17
// baseline (117.236 us; speedup 1.0000x reference)
//
#include <hip/hip_runtime.h>
#include <hip/hip_bf16.h>

// ConditionAttention: N=8, L=1024, EMBED=1024, HEADS=16, HEAD_DIM=64,
// POS_DIM=256, POS_PER_HEAD=16, POS_IDX=64.
// Pipeline: fused_pre (cvt_wo | pos_gemm | k_gemm | v_gemm | q_gemm[h<12],
// one launch) -> q_rest (heads 12-15, needs posb) -> flash attention
// (swapped-QK 32x32 MFMA, 64q/wave dual Q-group, 4-wave blocks, XCD swizzle,
// KVBLK=64 LDS dbuf + __syncthreads, static-max softmax) -> output GEMM
// (BK=64 dbuf, XCD-swizzled) + bias.
// Workspace: qb 16 | kb 16 | vT 16 | posb 4 | ob 16 | wo16 2 = 70MB.

typedef __hip_bfloat16 bf16;
typedef unsigned int u32;
typedef unsigned short u16;
typedef short short8 __attribute__((ext_vector_type(8)));
typedef float f32x4 __attribute__((ext_vector_type(4)));
typedef float f32x16 __attribute__((ext_vector_type(16)));
typedef unsigned int u32x2 __attribute__((ext_vector_type(2)));

#define MFMA16(a, b, c) __builtin_amdgcn_mfma_f32_16x16x32_bf16((a), (b), (c), 0, 0, 0)
#define MFMA32(a, b, c) __builtin_amdgcn_mfma_f32_32x32x16_bf16((a), (b), (c), 0, 0, 0)

// log2(e) / sqrt(EMBED) = 1.4426950408889634 / 32
#define QSCALE 0.04508422002777998f

__device__ __forceinline__ short8 ld8(const bf16* p) { return *(const short8*)p; }

__device__ __forceinline__ u32 pk2(float a, float b) {
  u16 ua = __bfloat16_as_ushort(__float2bfloat16(a));
  u16 ub = __bfloat16_as_ushort(__float2bfloat16(b));
  return (u32)ua | ((u32)ub << 16);
}

// raw v_exp_f32 (exp2), avoids ocml wrapper
__device__ __forceinline__ float fexp2(float x) {
  float r;
  asm("v_exp_f32 %0, %1" : "=v"(r) : "v"(x));
  return r;
}

// v_cvt_pk_bf16_f32: two f32 -> packed 2x bf16 in one u32
__device__ __forceinline__ u32 cvtpk(float a, float b) {
  u32 r;
  asm("v_cvt_pk_bf16_f32 %0, %1, %2" : "=v"(r) : "v"(a), "v"(b));
  return r;
}

// async global->LDS, 16B per lane; lds dest must be wave-uniform base
__device__ __forceinline__ void gload16(const void* g, void* l) {
  __builtin_amdgcn_global_load_lds(
      (const __attribute__((address_space(1))) u32*)g,
      (__attribute__((address_space(3))) u32*)l, 16, 0, 0);
}

union S8U { short8 s; u32 u[4]; };

// load 8 consecutive f32, convert to bf16 short8 fragment
__device__ __forceinline__ short8 ld8f(const float* p) {
  float4 a = ((const float4*)p)[0];
  float4 b = ((const float4*)p)[1];
  S8U r;
  r.u[0] = pk2(a.x, a.y);
  r.u[1] = pk2(a.z, a.w);
  r.u[2] = pk2(b.x, b.y);
  r.u[3] = pk2(b.z, b.w);
  return r.s;
}

// ---------------- fused_pre: cvt_wo | pos_gemm | k_gemm | v_gemm | q(h<12) --
// One launch, role by blockIdx.x range:
//   [0,128)      pos_gemm   (64 x 2 tile grid)
//   [128,1152)   k_gemm     (64 row-tiles x 16 heads)
//   [1152,2176)  v_gemm     (64 row-tiles x 16 heads, fused transpose)
//   [2176,2688)  cvt_wo     (1M f32->bf16, 2048 elems/block)
//   [2688,3456)  q_gemm h<12 (64 row-tiles x 12 heads; query-only cols)
// Shared LDS arena: 33280 B (= f32 slds[128][65]).
__global__ __launch_bounds__(256) void fused_pre(
    const float* __restrict__ position, const float* __restrict__ Wpos,
    const float* __restrict__ keys, const float* __restrict__ Wk,
    const float* __restrict__ values, const float* __restrict__ Wv,
    const float* __restrict__ Wo, const float* __restrict__ query,
    const float* __restrict__ Wq,
    bf16* __restrict__ posb, bf16* __restrict__ kb, bf16* __restrict__ vT,
    bf16* __restrict__ wo16, bf16* __restrict__ qb) {
  __shared__ __align__(16) char arena[33280];
  const int bidg = blockIdx.x;
  const int t = threadIdx.x;
  const int lane = t & 63, wave = t >> 6;
  const int g = lane >> 4, c = lane & 15;
  const int wr = wave >> 1, wc = wave & 1;

  if (bidg < 128) {
    // ---- pos_gemm ----
    const int px = bidg & 63, py = bidg >> 6;
    const int r0 = px * 128 + wr * 64;
    const int c0 = py * 128 + wc * 64;
    f32x4 acc[4][4];
#pragma unroll
    for (int ai = 0; ai < 4; ++ai)
#pragma unroll
      for (int bi = 0; bi < 4; ++bi) acc[ai][bi] = (f32x4){0.f, 0.f, 0.f, 0.f};
#pragma unroll
    for (int k0 = 0; k0 < 64; k0 += 32) {
      short8 af[4], bfr[4];
#pragma unroll
      for (int ai = 0; ai < 4; ++ai)
        af[ai] = ld8f(position + (size_t)(r0 + ai * 16 + c) * 64 + k0 + 8 * g);
#pragma unroll
      for (int bi = 0; bi < 4; ++bi)
        bfr[bi] = ld8f(Wpos + (size_t)(c0 + bi * 16 + c) * 64 + k0 + 8 * g);
#pragma unroll
      for (int ai = 0; ai < 4; ++ai)
#pragma unroll
        for (int bi = 0; bi < 4; ++bi) acc[ai][bi] = MFMA16(af[ai], bfr[bi], acc[ai][bi]);
    }
#pragma unroll
    for (int bi = 0; bi < 4; ++bi) {
      const int p = c0 + bi * 16 + c;
#pragma unroll
      for (int ai = 0; ai < 4; ++ai) {
#pragma unroll
        for (int i = 0; i < 4; ++i) {
          int row = r0 + ai * 16 + 4 * g + i;
          posb[(size_t)row * 256 + p] = __float2bfloat16(acc[ai][bi][i]);
        }
      }
    }
  } else if (bidg < 2176) {
    // ---- k_gemm (role 0) / v_gemm (role 1) ----
    const bool is_v = (bidg >= 1152);
    const int id = bidg - (is_v ? 1152 : 128);
    const int bx = id & 63, h = id >> 6;
    const float* src = is_v ? values : keys;
    const float* W = is_v ? Wv : Wk;
    f32x4 acc[4][2];
#pragma unroll
    for (int ai = 0; ai < 4; ++ai)
#pragma unroll
      for (int bi = 0; bi < 2; ++bi) acc[ai][bi] = (f32x4){0.f, 0.f, 0.f, 0.f};
    const int r0 = bx * 128;
    const int c0 = wc * 32;
#pragma unroll
    for (int k0 = 0; k0 < 64; k0 += 32) {
      short8 af[4], bfr[2];
#pragma unroll
      for (int ai = 0; ai < 4; ++ai)
        af[ai] = ld8f(src + (size_t)(r0 + wr * 64 + ai * 16 + c) * 1024 + 64 * h + k0 + 8 * g);
#pragma unroll
      for (int bi = 0; bi < 2; ++bi)
        bfr[bi] = ld8f(W + (size_t)(c0 + bi * 16 + c) * 64 + k0 + 8 * g);
#pragma unroll
      for (int ai = 0; ai < 4; ++ai)
#pragma unroll
        for (int bi = 0; bi < 2; ++bi) acc[ai][bi] = MFMA16(af[ai], bfr[bi], acc[ai][bi]);
    }
    if (!is_v) {
      // LDS-bounced coalesced K writes: [N,H,L,64]
      float (*slds)[65] = (float(*)[65])arena;
#pragma unroll
      for (int bi = 0; bi < 2; ++bi) {
        const int e = c0 + bi * 16 + c;
#pragma unroll
        for (int ai = 0; ai < 4; ++ai) {
#pragma unroll
          for (int i = 0; i < 4; ++i)
            slds[wr * 64 + ai * 16 + 4 * g + i][e] = acc[ai][bi][i];
        }
      }
      __syncthreads();
      const int n = r0 >> 10, lb = r0 & 1023;
      bf16* dstp = kb + ((size_t)(n * 16 + h) * 1024 + lb) * 64;
#pragma unroll
      for (int j = 0; j < 4; ++j) {
        const int id2 = t + j * 256;
        const int ll = id2 >> 3, e0 = (id2 & 7) * 8;
        const float* s = &slds[ll][e0];
        S8U r;
        r.u[0] = pk2(s[0], s[1]);
        r.u[1] = pk2(s[2], s[3]);
        r.u[2] = pk2(s[4], s[5]);
        r.u[3] = pk2(s[6], s[7]);
        *(short8*)(dstp + (size_t)ll * 64 + e0) = r.s;
      }
    } else {
      // fused-transpose V writes: [N,H,64,L]
      char* tlds = arena;  // 64 e-rows x 272 B
#pragma unroll
      for (int bi = 0; bi < 2; ++bi) {
        const int e_loc = c0 + bi * 16 + c;
#pragma unroll
        for (int ai = 0; ai < 4; ++ai) {
          const int l0 = wr * 64 + ai * 16 + 4 * g;
          *(u32*)(tlds + e_loc * 272 + l0 * 2) = pk2(acc[ai][bi][0], acc[ai][bi][1]);
          *(u32*)(tlds + e_loc * 272 + l0 * 2 + 4) = pk2(acc[ai][bi][2], acc[ai][bi][3]);
        }
      }
      __syncthreads();
      const int n = bx >> 3;
      const int lglob0 = (bx & 7) * 128;
      bf16* vbase = vT + ((size_t)(n * 16 + h)) * 64 * 1024;
#pragma unroll
      for (int j = 0; j < 4; ++j) {
        const int id2 = t + j * 256;
        const int e = id2 >> 4, lc = (id2 & 15) * 8;
        *(short8*)(vbase + (size_t)e * 1024 + lglob0 + lc) =
            *(const short8*)(tlds + e * 272 + lc * 2);
      }
    }
  } else if (bidg < 2688) {
    // ---- cvt_wo: 2048 f32 per block ----
    const int id = bidg - 2176;
    const int i8 = (id * 256 + t) * 8;
    *(short8*)(wo16 + i8) = ld8f(Wo + i8);
  } else {
    // ---- q_gemm for heads 0..11 (cols 80h..80h+79 all < 1024: query-only)
    const int id = bidg - 2688;
    const int bx = id & 63, h = id >> 6;  // h in 0..11
    const int r0 = bx * 128;
    const int c0 = wc * 32;
    f32x4 acc[4][2];
#pragma unroll
    for (int ai = 0; ai < 4; ++ai)
#pragma unroll
      for (int bi = 0; bi < 2; ++bi) acc[ai][bi] = (f32x4){0.f, 0.f, 0.f, 0.f};
    const short8 z8 = (short8){0, 0, 0, 0, 0, 0, 0, 0};
#pragma unroll
    for (int k0 = 0; k0 < 80; k0 += 32) {
      const bool tail_dead = (k0 == 64) && (g >= 2);
      const int col = 80 * h + k0 + 8 * g;
      short8 af[4], bfr[2];
#pragma unroll
      for (int ai = 0; ai < 4; ++ai) {
        const int row = r0 + wr * 64 + ai * 16 + c;
        af[ai] = tail_dead ? z8 : ld8f(query + (size_t)row * 1024 + col);
      }
#pragma unroll
      for (int bi = 0; bi < 2; ++bi)
        bfr[bi] = tail_dead ? z8
                            : ld8f(Wq + (size_t)(c0 + bi * 16 + c) * 80 + k0 + 8 * g);
#pragma unroll
      for (int ai = 0; ai < 4; ++ai)
#pragma unroll
        for (int bi = 0; bi < 2; ++bi) acc[ai][bi] = MFMA16(af[ai], bfr[bi], acc[ai][bi]);
    }
    float (*slds)[65] = (float(*)[65])arena;
#pragma unroll
    for (int bi = 0; bi < 2; ++bi) {
      const int e = c0 + bi * 16 + c;
#pragma unroll
      for (int ai = 0; ai < 4; ++ai) {
#pragma unroll
        for (int i = 0; i < 4; ++i)
          slds[wr * 64 + ai * 16 + 4 * g + i][e] = acc[ai][bi][i] * QSCALE;
      }
    }
    __syncthreads();
    const int n = r0 >> 10, lb = r0 & 1023;
    bf16* dstp = qb + ((size_t)(n * 16 + h) * 1024 + lb) * 64;
#pragma unroll
    for (int j = 0; j < 4; ++j) {
      const int id2 = t + j * 256;
      const int ll = id2 >> 3, e0 = (id2 & 7) * 8;
      const float* s = &slds[ll][e0];
      S8U r;
      r.u[0] = pk2(s[0], s[1]);
      r.u[1] = pk2(s[2], s[3]);
      r.u[2] = pk2(s[4], s[5]);
      r.u[3] = pk2(s[6], s[7]);
      *(short8*)(dstp + (size_t)ll * 64 + e0) = r.s;
    }
  }
}

// ---------------- q_rest: q projection for heads 12..15 (needs posb) -------
__global__ __launch_bounds__(256) void q_rest(const float* __restrict__ query,
                                              const bf16* __restrict__ posb,
                                              const float* __restrict__ Wq,
                                              bf16* __restrict__ qb) {
  __shared__ float slds[128][65];
  const int t = threadIdx.x;
  const int lane = t & 63, wave = t >> 6;
  const int g = lane >> 4, c = lane & 15;
  const int wr = wave >> 1, wc = wave & 1;
  const int r0 = blockIdx.x * 128;
  const int c0 = wc * 32;
  const int h = blockIdx.y + 12;
  f32x4 acc[4][2];
#pragma unroll
  for (int ai = 0; ai < 4; ++ai)
#pragma unroll
    for (int bi = 0; bi < 2; ++bi) acc[ai][bi] = (f32x4){0.f, 0.f, 0.f, 0.f};
  const short8 z8 = (short8){0, 0, 0, 0, 0, 0, 0, 0};
#pragma unroll
  for (int k0 = 0; k0 < 80; k0 += 32) {
    const bool tail_dead = (k0 == 64) && (g >= 2);
    const int col = 80 * h + k0 + 8 * g;
    short8 af[4], bfr[2];
#pragma unroll
    for (int ai = 0; ai < 4; ++ai) {
      const int row = r0 + wr * 64 + ai * 16 + c;
      af[ai] = tail_dead ? z8
               : (col < 1024 ? ld8f(query + (size_t)row * 1024 + col)
                             : ld8(posb + (size_t)row * 256 + (col - 1024)));
    }
#pragma unroll
    for (int bi = 0; bi < 2; ++bi)
      bfr[bi] = tail_dead ? z8
                          : ld8f(Wq + (size_t)(c0 + bi * 16 + c) * 80 + k0 + 8 * g);
#pragma unroll
    for (int ai = 0; ai < 4; ++ai)
#pragma unroll
      for (int bi = 0; bi < 2; ++bi) acc[ai][bi] = MFMA16(af[ai], bfr[bi], acc[ai][bi]);
  }
#pragma unroll
  for (int bi = 0; bi < 2; ++bi) {
    const int e = c0 + bi * 16 + c;
#pragma unroll
    for (int ai = 0; ai < 4; ++ai) {
#pragma unroll
      for (int i = 0; i < 4; ++i)
        slds[wr * 64 + ai * 16 + 4 * g + i][e] = acc[ai][bi][i] * QSCALE;
    }
  }
  __syncthreads();
  const int n = r0 >> 10, lb = r0 & 1023;
  bf16* dstp = qb + ((size_t)(n * 16 + h) * 1024 + lb) * 64;
#pragma unroll
  for (int j = 0; j < 4; ++j) {
    const int id = t + j * 256;
    const int ll = id >> 3, e0 = (id & 7) * 8;
    const float* s = &slds[ll][e0];
    S8U r;
    r.u[0] = pk2(s[0], s[1]);
    r.u[1] = pk2(s[2], s[3]);
    r.u[2] = pk2(s[4], s[5]);
    r.u[3] = pk2(s[6], s[7]);
    *(short8*)(dstp + (size_t)ll * 64 + e0) = r.s;
  }
}

// ---------------- flash attention: 64q/wave, 4-wave blocks + XCD swz --------
// (R12/R15-proven body: KVBLK=64, 2x16KB dbuf, __syncthreads, 116 VGPR.)
__global__ __launch_bounds__(256, 2) void attn_kernel(const bf16* __restrict__ qb,
                                                      const bf16* __restrict__ kb,
                                                      const bf16* __restrict__ vT,
                                                      bf16* __restrict__ ob) {
  __shared__ __align__(16) char smem[2][16384];  // per buf: K 8KB | V 8KB
  const int t = threadIdx.x;
  const int lane = t & 63, wave = t >> 6;
  const int l31 = lane & 31, hi = lane >> 5;
  const int bid = blockIdx.x;                    // 0..511
  const int w = (bid & 7) * 64 + (bid >> 3);     // XCD-contiguous work id
  const int qt = w & 3, h = (w >> 2) & 15, n = w >> 6;
  const int nh = n * 16 + h;
  const int q0 = qt * 256 + wave * 64;

  const bf16* kpan = kb + (size_t)nh * 65536;
  const bf16* vpan = vT + (size_t)nh * 65536;

  const int sr8 = lane >> 3;
  const int scg = (lane & 7) ^ sr8;
  const int row0 = wave * 8 + sr8;
  const bf16* kgA = kpan + (size_t)row0 * 64 + scg * 8;
  const bf16* kgB = kpan + (size_t)(32 + row0) * 64 + scg * 8;
  const bf16* vgA = vpan + (size_t)row0 * 1024 + scg * 8;
  const bf16* vgB = vpan + (size_t)(32 + row0) * 1024 + scg * 8;
  const int ldsoff = wave * 1024;

  const bf16* qrowA = qb + ((size_t)nh * 1024 + q0 + l31) * 64 + 8 * hi;
  const bf16* qrowB = qrowA + 32 * 64;
  short8 qfA[4], qfB[4];
#pragma unroll
  for (int ds = 0; ds < 4; ++ds) {
    qfA[ds] = ld8(qrowA + ds * 16);
    qfB[ds] = ld8(qrowB + ds * 16);
  }

  f32x16 accA0, accA1, accB0, accB1;
#pragma unroll
  for (int r = 0; r < 16; ++r) {
    accA0[r] = 0.f;
    accA1[r] = 0.f;
    accB0[r] = 0.f;
    accB1[r] = 0.f;
  }
  float lA = 0.f, lB = 0.f;

  gload16(kgA, smem[0] + ldsoff);
  gload16(kgB, smem[0] + 4096 + ldsoff);
  gload16(vgA, smem[0] + 8192 + ldsoff);
  gload16(vgB, smem[0] + 12288 + ldsoff);
  __syncthreads();

  int cur = 0;
  for (int kt = 0; kt < 16; ++kt) {
    if (kt < 15) {
      char* sn = smem[cur ^ 1];
      const size_t ko = (size_t)(kt + 1) * 4096;
      const int vo = (kt + 1) * 64;
      gload16(kgA + ko, sn + ldsoff);
      gload16(kgB + ko, sn + 4096 + ldsoff);
      gload16(vgA + vo, sn + 8192 + ldsoff);
      gload16(vgB + vo, sn + 12288 + ldsoff);
    }
    const char* kt_ = smem[cur];
    const char* vt_ = smem[cur] + 8192;

#pragma unroll
    for (int s = 0; s < 2; ++s) {
      const int kr = s * 32 + l31;
      short8 kf[4], vf[2][2];
#pragma unroll
      for (int ds = 0; ds < 4; ++ds)
        kf[ds] = *(const short8*)(kt_ + kr * 128 + (((2 * ds + hi) ^ (kr & 7)) << 4));
#pragma unroll
      for (int dt = 0; dt < 2; ++dt) {
        const int vr = dt * 32 + l31;
#pragma unroll
        for (int ks = 0; ks < 2; ++ks)
          vf[dt][ks] = *(const short8*)(
              vt_ + vr * 128 + (((s * 4 + ks * 2 + hi) ^ (vr & 7)) << 4));
      }

      f32x16 srA, srB;
#pragma unroll
      for (int r = 0; r < 16; ++r) {
        srA[r] = 0.f;
        srB[r] = 0.f;
      }
      __builtin_amdgcn_s_setprio(1);
      srA = MFMA32(kf[0], qfA[0], srA);
      srA = MFMA32(kf[1], qfA[1], srA);
      srA = MFMA32(kf[2], qfA[2], srA);
      srA = MFMA32(kf[3], qfA[3], srA);
      srB = MFMA32(kf[0], qfB[0], srB);
      srB = MFMA32(kf[1], qfB[1], srB);
      srB = MFMA32(kf[2], qfB[2], srB);
      srB = MFMA32(kf[3], qfB[3], srB);
      __builtin_amdgcn_s_setprio(0);

      float pA[16], pB[16];
#pragma unroll
      for (int r = 0; r < 16; ++r) pA[r] = fexp2(srA[r]);
#pragma unroll
      for (int r = 0; r < 16; ++r) pB[r] = fexp2(srB[r]);

      u32 a01 = cvtpk(pA[0], pA[1]), a23 = cvtpk(pA[2], pA[3]);
      u32 a45 = cvtpk(pA[4], pA[5]), a67 = cvtpk(pA[6], pA[7]);
      u32 a89 = cvtpk(pA[8], pA[9]), aab = cvtpk(pA[10], pA[11]);
      u32 acd = cvtpk(pA[12], pA[13]), aef = cvtpk(pA[14], pA[15]);
      u32x2 sa0 = __builtin_amdgcn_permlane32_swap(a01, a45, false, false);
      u32x2 sa1 = __builtin_amdgcn_permlane32_swap(a23, a67, false, false);
      u32x2 sa2 = __builtin_amdgcn_permlane32_swap(a89, acd, false, false);
      u32x2 sa3 = __builtin_amdgcn_permlane32_swap(aab, aef, false, false);
      S8U pfA0, pfA1;
      pfA0.u[0] = sa0[0];
      pfA0.u[1] = sa1[0];
      pfA0.u[2] = sa0[1];
      pfA0.u[3] = sa1[1];
      pfA1.u[0] = sa2[0];
      pfA1.u[1] = sa3[0];
      pfA1.u[2] = sa2[1];
      pfA1.u[3] = sa3[1];

      u32 b01 = cvtpk(pB[0], pB[1]), b23 = cvtpk(pB[2], pB[3]);
      u32 b45 = cvtpk(pB[4], pB[5]), b67 = cvtpk(pB[6], pB[7]);
      u32 b89 = cvtpk(pB[8], pB[9]), bab = cvtpk(pB[10], pB[11]);
      u32 bcd = cvtpk(pB[12], pB[13]), bef = cvtpk(pB[14], pB[15]);
      u32x2 sb0 = __builtin_amdgcn_permlane32_swap(b01, b45, false, false);
      u32x2 sb1 = __builtin_amdgcn_permlane32_swap(b23, b67, false, false);
      u32x2 sb2 = __builtin_amdgcn_permlane32_swap(b89, bcd, false, false);
      u32x2 sb3 = __builtin_amdgcn_permlane32_swap(bab, bef, false, false);
      S8U pfB0, pfB1;
      pfB0.u[0] = sb0[0];
      pfB0.u[1] = sb1[0];
      pfB0.u[2] = sb0[1];
      pfB0.u[3] = sb1[1];
      pfB1.u[0] = sb2[0];
      pfB1.u[1] = sb3[0];
      pfB1.u[2] = sb2[1];
      pfB1.u[3] = sb3[1];

      __builtin_amdgcn_s_setprio(1);
      accA0 = MFMA32(vf[0][0], pfA0.s, accA0);
      accA0 = MFMA32(vf[0][1], pfA1.s, accA0);
      accA1 = MFMA32(vf[1][0], pfA0.s, accA1);
      accA1 = MFMA32(vf[1][1], pfA1.s, accA1);
      accB0 = MFMA32(vf[0][0], pfB0.s, accB0);
      accB0 = MFMA32(vf[0][1], pfB1.s, accB0);
      accB1 = MFMA32(vf[1][0], pfB0.s, accB1);
      accB1 = MFMA32(vf[1][1], pfB1.s, accB1);
      __builtin_amdgcn_s_setprio(0);

      float psA = ((pA[0] + pA[1]) + (pA[2] + pA[3])) +
                  ((pA[4] + pA[5]) + (pA[6] + pA[7])) +
                  ((pA[8] + pA[9]) + (pA[10] + pA[11])) +
                  ((pA[12] + pA[13]) + (pA[14] + pA[15]));
      float psB = ((pB[0] + pB[1]) + (pB[2] + pB[3])) +
                  ((pB[4] + pB[5]) + (pB[6] + pB[7])) +
                  ((pB[8] + pB[9]) + (pB[10] + pB[11])) +
                  ((pB[12] + pB[13]) + (pB[14] + pB[15]));
      psA += __shfl_xor(psA, 32);
      psB += __shfl_xor(psB, 32);
      lA += psA;
      lB += psB;
    }
    __syncthreads();
    cur ^= 1;
  }

  const float invA = 1.f / lA, invB = 1.f / lB;
  bf16* obaseA = ob + ((size_t)(n * 1024 + q0 + l31) * 16 + h) * 64;
  bf16* obaseB = obaseA + (size_t)32 * 16 * 64;
#pragma unroll
  for (int dt = 0; dt < 2; ++dt) {
#pragma unroll
    for (int rb = 0; rb < 4; ++rb) {
      const int d0 = dt * 32 + rb * 8 + 4 * hi;
      const f32x16& aA = dt ? accA1 : accA0;
      const f32x16& aB = dt ? accB1 : accB0;
      u32x2 wA, wB;
      wA[0] = pk2(aA[4 * rb + 0] * invA, aA[4 * rb + 1] * invA);
      wA[1] = pk2(aA[4 * rb + 2] * invA, aA[4 * rb + 3] * invA);
      wB[0] = pk2(aB[4 * rb + 0] * invB, aB[4 * rb + 1] * invB);
      wB[1] = pk2(aB[4 * rb + 2] * invB, aB[4 * rb + 3] * invB);
      *(u32x2*)(obaseA + d0) = wA;
      *(u32x2*)(obaseB + d0) = wB;
    }
  }
}

// ---------------- output GEMM  out = A @ Wo^T + bo  (BK=64, XCD-swizzled) ----
__global__ __launch_bounds__(256) void out_gemm(const bf16* __restrict__ A,
                                                const bf16* __restrict__ B,
                                                const float* __restrict__ bias,
                                                float* __restrict__ out) {
  __shared__ __align__(16) char smem[2][32768];  // per buf: A 16KB | B 16KB
  const int t = threadIdx.x;
  const int lane = t & 63, wave = t >> 6;
  const int g = lane >> 4, c = lane & 15;
  const int wr = wave >> 1, wc = wave & 1;
  const int bid = blockIdx.x;                    // 0..511
  const int w = (bid & 7) * 64 + (bid >> 3);     // XCD-contiguous work id
  const int r0 = (w >> 3) * 128;                 // row tile (64 values)
  const int c0 = (w & 7) * 128;                  // col tile (8 values)

  const int sr8 = lane >> 3;
  const int scg = (lane & 7) ^ sr8;
  const int row0 = wave * 8 + sr8;
  const bf16* ag = A + (size_t)(r0 + row0) * 1024 + scg * 8;
  const bf16* bg = B + (size_t)(c0 + row0) * 1024 + scg * 8;
  const int ldsoff = wave * 1024;

  f32x4 acc[4][4];
#pragma unroll
  for (int ai = 0; ai < 4; ++ai)
#pragma unroll
    for (int bi = 0; bi < 4; ++bi) acc[ai][bi] = (f32x4){0.f, 0.f, 0.f, 0.f};

#pragma unroll
  for (int j = 0; j < 4; ++j) {
    gload16(ag + (size_t)j * 32 * 1024, smem[0] + j * 4096 + ldsoff);
    gload16(bg + (size_t)j * 32 * 1024, smem[0] + 16384 + j * 4096 + ldsoff);
  }
  __syncthreads();

  int cur = 0;
  for (int kt = 0; kt < 16; ++kt) {
    if (kt < 15) {
      char* sn = smem[cur ^ 1];
      const int k1 = (kt + 1) * 64;
#pragma unroll
      for (int j = 0; j < 4; ++j) {
        gload16(ag + (size_t)j * 32 * 1024 + k1, sn + j * 4096 + ldsoff);
        gload16(bg + (size_t)j * 32 * 1024 + k1, sn + 16384 + j * 4096 + ldsoff);
      }
    }
    const char* sa = smem[cur];
    const char* sb = smem[cur] + 16384;

#pragma unroll
    for (int h2 = 0; h2 < 2; ++h2) {
      short8 af[4], bfr[4];
#pragma unroll
      for (int ai = 0; ai < 4; ++ai) {
        const int row = wr * 64 + ai * 16 + c;
        af[ai] = *(const short8*)(sa + row * 128 + (((h2 * 4 + g) ^ (row & 7)) << 4));
      }
#pragma unroll
      for (int bi = 0; bi < 4; ++bi) {
        const int row = wc * 64 + bi * 16 + c;
        bfr[bi] = *(const short8*)(sb + row * 128 + (((h2 * 4 + g) ^ (row & 7)) << 4));
      }
      __builtin_amdgcn_s_setprio(1);
#pragma unroll
      for (int ai = 0; ai < 4; ++ai)
#pragma unroll
        for (int bi = 0; bi < 4; ++bi) acc[ai][bi] = MFMA16(af[ai], bfr[bi], acc[ai][bi]);
      __builtin_amdgcn_s_setprio(0);
    }

    __syncthreads();
    cur ^= 1;
  }

#pragma unroll
  for (int bi = 0; bi < 4; ++bi) {
    const int e = c0 + wc * 64 + bi * 16 + c;
    const float bv = bias[e];
#pragma unroll
    for (int ai = 0; ai < 4; ++ai) {
#pragma unroll
      for (int i = 0; i < 4; ++i) {
        out[(size_t)(r0 + wr * 64 + ai * 16 + 4 * g + i) * 1024 + e] =
            acc[ai][bi][i] + bv;
      }
    }
  }
}

extern "C" void kernel_launch(void* const* d_in, const int* in_sizes, int n_in,
                              void* d_out, int out_size, void* d_ws, size_t ws_size,
                              hipStream_t stream) {
  const float* values = (const float*)d_in[0];
  const float* keys = (const float*)d_in[1];
  const float* query = (const float*)d_in[2];
  const float* position = (const float*)d_in[3];
  const float* Wv = (const float*)d_in[4];
  const float* Wk = (const float*)d_in[5];
  const float* Wq = (const float*)d_in[6];
  const float* Wpos = (const float*)d_in[7];
  const float* Wo = (const float*)d_in[8];
  const float* bo = (const float*)d_in[9];

  char* ws = (char*)d_ws;
  bf16* qb = (bf16*)(ws);                          // 16MB
  bf16* kb = (bf16*)(ws + ((size_t)16 << 20));     // 16MB
  bf16* vT = (bf16*)(ws + ((size_t)32 << 20));     // 16MB
  bf16* posb = (bf16*)(ws + ((size_t)48 << 20));   // 4MB [8192][256]
  bf16* ob = (bf16*)(ws + ((size_t)52 << 20));     // 16MB
  bf16* wo16 = (bf16*)(ws + ((size_t)68 << 20));   // 2MB
  float* out = (float*)d_out;

  fused_pre<<<3456, 256, 0, stream>>>(position, Wpos, keys, Wk, values, Wv, Wo,
                                      query, Wq, posb, kb, vT, wo16, qb);
  q_rest<<<dim3(64, 4), 256, 0, stream>>>(query, posb, Wq, qb);
  attn_kernel<<<512, 256, 0, stream>>>(qb, kb, vT, ob);
  out_gemm<<<512, 256, 0, stream>>>(ob, wo16, bo, out);
}

// Round 18
// 113.172 us; speedup vs baseline: 1.0359x; 1.0359x over previous
//
#include <hip/hip_runtime.h>
#include <hip/hip_bf16.h>

// ConditionAttention: N=8, L=1024, EMBED=1024, HEADS=16, HEAD_DIM=64,
// POS_DIM=256, POS_PER_HEAD=16, POS_IDX=64.
// Pipeline: fused_pre (cvt_wo | pos_gemm | k_gemm | v_gemm role-dispatched,
// one launch) -> q_gemm(dual-source query/posb) -> flash attention
// (swapped-QK 32x32 MFMA, 64q/wave dual Q-group, 4-wave blocks, XCD swizzle,
// KVBLK=64 LDS dbuf + __syncthreads, static-max softmax) -> output GEMM
// (LDS-staged BK=64 dbuf, swizzled, XCD-swizzled grid) + bias.
// Workspace: qb 16 | kb 16 | vT 16 | posb 4 | ob 16 | wo16 2 = 70MB.
// (R18 = exact revert to the best-measured R15 configuration, 113.8us.)

typedef __hip_bfloat16 bf16;
typedef unsigned int u32;
typedef unsigned short u16;
typedef short short8 __attribute__((ext_vector_type(8)));
typedef float f32x4 __attribute__((ext_vector_type(4)));
typedef float f32x16 __attribute__((ext_vector_type(16)));
typedef unsigned int u32x2 __attribute__((ext_vector_type(2)));

#define MFMA16(a, b, c) __builtin_amdgcn_mfma_f32_16x16x32_bf16((a), (b), (c), 0, 0, 0)
#define MFMA32(a, b, c) __builtin_amdgcn_mfma_f32_32x32x16_bf16((a), (b), (c), 0, 0, 0)

// log2(e) / sqrt(EMBED) = 1.4426950408889634 / 32
#define QSCALE 0.04508422002777998f

__device__ __forceinline__ short8 ld8(const bf16* p) { return *(const short8*)p; }

__device__ __forceinline__ u32 pk2(float a, float b) {
  u16 ua = __bfloat16_as_ushort(__float2bfloat16(a));
  u16 ub = __bfloat16_as_ushort(__float2bfloat16(b));
  return (u32)ua | ((u32)ub << 16);
}

// raw v_exp_f32 (exp2), avoids ocml wrapper
__device__ __forceinline__ float fexp2(float x) {
  float r;
  asm("v_exp_f32 %0, %1" : "=v"(r) : "v"(x));
  return r;
}

// v_cvt_pk_bf16_f32: two f32 -> packed 2x bf16 in one u32
__device__ __forceinline__ u32 cvtpk(float a, float b) {
  u32 r;
  asm("v_cvt_pk_bf16_f32 %0, %1, %2" : "=v"(r) : "v"(a), "v"(b));
  return r;
}

// async global->LDS, 16B per lane; lds dest must be wave-uniform base
__device__ __forceinline__ void gload16(const void* g, void* l) {
  __builtin_amdgcn_global_load_lds(
      (const __attribute__((address_space(1))) u32*)g,
      (__attribute__((address_space(3))) u32*)l, 16, 0, 0);
}

union S8U { short8 s; u32 u[4]; };

// load 8 consecutive f32, convert to bf16 short8 fragment
__device__ __forceinline__ short8 ld8f(const float* p) {
  float4 a = ((const float4*)p)[0];
  float4 b = ((const float4*)p)[1];
  S8U r;
  r.u[0] = pk2(a.x, a.y);
  r.u[1] = pk2(a.z, a.w);
  r.u[2] = pk2(b.x, b.y);
  r.u[3] = pk2(b.z, b.w);
  return r.s;
}

// ---------------- fused_pre: cvt_wo | pos_gemm | k_gemm | v_gemm ------------
// One launch, role by blockIdx.x range:
//   [0,128)      pos_gemm   (64 x 2 tile grid)
//   [128,1152)   k_gemm     (64 row-tiles x 16 heads)
//   [1152,2176)  v_gemm     (64 row-tiles x 16 heads, fused transpose)
//   [2176,2688)  cvt_wo     (1M f32->bf16, 2048 elems/block)
// Shared LDS arena: max(k slds 33280, v tlds 17408) = 33280 B.
__global__ __launch_bounds__(256) void fused_pre(
    const float* __restrict__ position, const float* __restrict__ Wpos,
    const float* __restrict__ keys, const float* __restrict__ Wk,
    const float* __restrict__ values, const float* __restrict__ Wv,
    const float* __restrict__ Wo,
    bf16* __restrict__ posb, bf16* __restrict__ kb, bf16* __restrict__ vT,
    bf16* __restrict__ wo16) {
  __shared__ __align__(16) char arena[33280];
  const int bidg = blockIdx.x;
  const int t = threadIdx.x;
  const int lane = t & 63, wave = t >> 6;
  const int g = lane >> 4, c = lane & 15;
  const int wr = wave >> 1, wc = wave & 1;

  if (bidg < 128) {
    // ---- pos_gemm ----
    const int px = bidg & 63, py = bidg >> 6;
    const int r0 = px * 128 + wr * 64;
    const int c0 = py * 128 + wc * 64;
    f32x4 acc[4][4];
#pragma unroll
    for (int ai = 0; ai < 4; ++ai)
#pragma unroll
      for (int bi = 0; bi < 4; ++bi) acc[ai][bi] = (f32x4){0.f, 0.f, 0.f, 0.f};
#pragma unroll
    for (int k0 = 0; k0 < 64; k0 += 32) {
      short8 af[4], bfr[4];
#pragma unroll
      for (int ai = 0; ai < 4; ++ai)
        af[ai] = ld8f(position + (size_t)(r0 + ai * 16 + c) * 64 + k0 + 8 * g);
#pragma unroll
      for (int bi = 0; bi < 4; ++bi)
        bfr[bi] = ld8f(Wpos + (size_t)(c0 + bi * 16 + c) * 64 + k0 + 8 * g);
#pragma unroll
      for (int ai = 0; ai < 4; ++ai)
#pragma unroll
        for (int bi = 0; bi < 4; ++bi) acc[ai][bi] = MFMA16(af[ai], bfr[bi], acc[ai][bi]);
    }
#pragma unroll
    for (int bi = 0; bi < 4; ++bi) {
      const int p = c0 + bi * 16 + c;
#pragma unroll
      for (int ai = 0; ai < 4; ++ai) {
#pragma unroll
        for (int i = 0; i < 4; ++i) {
          int row = r0 + ai * 16 + 4 * g + i;
          posb[(size_t)row * 256 + p] = __float2bfloat16(acc[ai][bi][i]);
        }
      }
    }
  } else if (bidg < 2176) {
    // ---- k_gemm (role 0) / v_gemm (role 1) ----
    const bool is_v = (bidg >= 1152);
    const int id = bidg - (is_v ? 1152 : 128);
    const int bx = id & 63, h = id >> 6;
    const float* src = is_v ? values : keys;
    const float* W = is_v ? Wv : Wk;
    f32x4 acc[4][2];
#pragma unroll
    for (int ai = 0; ai < 4; ++ai)
#pragma unroll
      for (int bi = 0; bi < 2; ++bi) acc[ai][bi] = (f32x4){0.f, 0.f, 0.f, 0.f};
    const int r0 = bx * 128;
    const int c0 = wc * 32;
#pragma unroll
    for (int k0 = 0; k0 < 64; k0 += 32) {
      short8 af[4], bfr[2];
#pragma unroll
      for (int ai = 0; ai < 4; ++ai)
        af[ai] = ld8f(src + (size_t)(r0 + wr * 64 + ai * 16 + c) * 1024 + 64 * h + k0 + 8 * g);
#pragma unroll
      for (int bi = 0; bi < 2; ++bi)
        bfr[bi] = ld8f(W + (size_t)(c0 + bi * 16 + c) * 64 + k0 + 8 * g);
#pragma unroll
      for (int ai = 0; ai < 4; ++ai)
#pragma unroll
        for (int bi = 0; bi < 2; ++bi) acc[ai][bi] = MFMA16(af[ai], bfr[bi], acc[ai][bi]);
    }
    if (!is_v) {
      // LDS-bounced coalesced K writes: [N,H,L,64]
      float (*slds)[65] = (float(*)[65])arena;
#pragma unroll
      for (int bi = 0; bi < 2; ++bi) {
        const int e = c0 + bi * 16 + c;
#pragma unroll
        for (int ai = 0; ai < 4; ++ai) {
#pragma unroll
          for (int i = 0; i < 4; ++i)
            slds[wr * 64 + ai * 16 + 4 * g + i][e] = acc[ai][bi][i];
        }
      }
      __syncthreads();
      const int n = r0 >> 10, lb = r0 & 1023;
      bf16* dstp = kb + ((size_t)(n * 16 + h) * 1024 + lb) * 64;
#pragma unroll
      for (int j = 0; j < 4; ++j) {
        const int id2 = t + j * 256;
        const int ll = id2 >> 3, e0 = (id2 & 7) * 8;
        const float* s = &slds[ll][e0];
        S8U r;
        r.u[0] = pk2(s[0], s[1]);
        r.u[1] = pk2(s[2], s[3]);
        r.u[2] = pk2(s[4], s[5]);
        r.u[3] = pk2(s[6], s[7]);
        *(short8*)(dstp + (size_t)ll * 64 + e0) = r.s;
      }
    } else {
      // fused-transpose V writes: [N,H,64,L]
      char* tlds = arena;  // 64 e-rows x 272 B
#pragma unroll
      for (int bi = 0; bi < 2; ++bi) {
        const int e_loc = c0 + bi * 16 + c;
#pragma unroll
        for (int ai = 0; ai < 4; ++ai) {
          const int l0 = wr * 64 + ai * 16 + 4 * g;
          *(u32*)(tlds + e_loc * 272 + l0 * 2) = pk2(acc[ai][bi][0], acc[ai][bi][1]);
          *(u32*)(tlds + e_loc * 272 + l0 * 2 + 4) = pk2(acc[ai][bi][2], acc[ai][bi][3]);
        }
      }
      __syncthreads();
      const int n = bx >> 3;
      const int lglob0 = (bx & 7) * 128;
      bf16* vbase = vT + ((size_t)(n * 16 + h)) * 64 * 1024;
#pragma unroll
      for (int j = 0; j < 4; ++j) {
        const int id2 = t + j * 256;
        const int e = id2 >> 4, lc = (id2 & 15) * 8;
        *(short8*)(vbase + (size_t)e * 1024 + lglob0 + lc) =
            *(const short8*)(tlds + e * 272 + lc * 2);
      }
    }
  } else {
    // ---- cvt_wo: 2048 f32 per block ----
    const int id = bidg - 2176;
    const int i8 = (id * 256 + t) * 8;
    *(short8*)(wo16 + i8) = ld8f(Wo + i8);
  }
}

// ---------------- q_gemm: per-head q projection, LDS-bounced writes ---------
__global__ __launch_bounds__(256) void q_gemm(const float* __restrict__ query,
                                              const bf16* __restrict__ posb,
                                              const float* __restrict__ Wq,
                                              bf16* __restrict__ qb) {
  __shared__ float slds[128][65];
  const int t = threadIdx.x;
  const int lane = t & 63, wave = t >> 6;
  const int g = lane >> 4, c = lane & 15;
  const int wr = wave >> 1, wc = wave & 1;
  const int r0 = blockIdx.x * 128;
  const int c0 = wc * 32;
  const int h = blockIdx.y;
  f32x4 acc[4][2];
#pragma unroll
  for (int ai = 0; ai < 4; ++ai)
#pragma unroll
    for (int bi = 0; bi < 2; ++bi) acc[ai][bi] = (f32x4){0.f, 0.f, 0.f, 0.f};
  const short8 z8 = (short8){0, 0, 0, 0, 0, 0, 0, 0};
#pragma unroll
  for (int k0 = 0; k0 < 80; k0 += 32) {
    const bool tail_dead = (k0 == 64) && (g >= 2);
    const int col = 80 * h + k0 + 8 * g;
    short8 af[4], bfr[2];
#pragma unroll
    for (int ai = 0; ai < 4; ++ai) {
      const int row = r0 + wr * 64 + ai * 16 + c;
      af[ai] = tail_dead ? z8
               : (col < 1024 ? ld8f(query + (size_t)row * 1024 + col)
                             : ld8(posb + (size_t)row * 256 + (col - 1024)));
    }
#pragma unroll
    for (int bi = 0; bi < 2; ++bi)
      bfr[bi] = tail_dead ? z8
                          : ld8f(Wq + (size_t)(c0 + bi * 16 + c) * 80 + k0 + 8 * g);
#pragma unroll
    for (int ai = 0; ai < 4; ++ai)
#pragma unroll
      for (int bi = 0; bi < 2; ++bi) acc[ai][bi] = MFMA16(af[ai], bfr[bi], acc[ai][bi]);
  }
#pragma unroll
  for (int bi = 0; bi < 2; ++bi) {
    const int e = c0 + bi * 16 + c;
#pragma unroll
    for (int ai = 0; ai < 4; ++ai) {
#pragma unroll
      for (int i = 0; i < 4; ++i)
        slds[wr * 64 + ai * 16 + 4 * g + i][e] = acc[ai][bi][i] * QSCALE;
    }
  }
  __syncthreads();
  const int n = r0 >> 10, lb = r0 & 1023;
  bf16* dstp = qb + ((size_t)(n * 16 + h) * 1024 + lb) * 64;
#pragma unroll
  for (int j = 0; j < 4; ++j) {
    const int id = t + j * 256;
    const int ll = id >> 3, e0 = (id & 7) * 8;
    const float* s = &slds[ll][e0];
    S8U r;
    r.u[0] = pk2(s[0], s[1]);
    r.u[1] = pk2(s[2], s[3]);
    r.u[2] = pk2(s[4], s[5]);
    r.u[3] = pk2(s[6], s[7]);
    *(short8*)(dstp + (size_t)ll * 64 + e0) = r.s;
  }
}

// ---------------- flash attention: 64q/wave, 4-wave blocks + XCD swz --------
// (R12-proven body: KVBLK=64, 2x16KB dbuf, __syncthreads skeleton, 116 VGPR.)
__global__ __launch_bounds__(256, 2) void attn_kernel(const bf16* __restrict__ qb,
                                                      const bf16* __restrict__ kb,
                                                      const bf16* __restrict__ vT,
                                                      bf16* __restrict__ ob) {
  __shared__ __align__(16) char smem[2][16384];  // per buf: K 8KB | V 8KB
  const int t = threadIdx.x;
  const int lane = t & 63, wave = t >> 6;
  const int l31 = lane & 31, hi = lane >> 5;
  const int bid = blockIdx.x;                    // 0..511
  const int w = (bid & 7) * 64 + (bid >> 3);     // XCD-contiguous work id
  const int qt = w & 3, h = (w >> 2) & 15, n = w >> 6;
  const int nh = n * 16 + h;
  const int q0 = qt * 256 + wave * 64;

  const bf16* kpan = kb + (size_t)nh * 65536;
  const bf16* vpan = vT + (size_t)nh * 65536;

  const int sr8 = lane >> 3;
  const int scg = (lane & 7) ^ sr8;
  const int row0 = wave * 8 + sr8;
  const bf16* kgA = kpan + (size_t)row0 * 64 + scg * 8;
  const bf16* kgB = kpan + (size_t)(32 + row0) * 64 + scg * 8;
  const bf16* vgA = vpan + (size_t)row0 * 1024 + scg * 8;
  const bf16* vgB = vpan + (size_t)(32 + row0) * 1024 + scg * 8;
  const int ldsoff = wave * 1024;

  const bf16* qrowA = qb + ((size_t)nh * 1024 + q0 + l31) * 64 + 8 * hi;
  const bf16* qrowB = qrowA + 32 * 64;
  short8 qfA[4], qfB[4];
#pragma unroll
  for (int ds = 0; ds < 4; ++ds) {
    qfA[ds] = ld8(qrowA + ds * 16);
    qfB[ds] = ld8(qrowB + ds * 16);
  }

  f32x16 accA0, accA1, accB0, accB1;
#pragma unroll
  for (int r = 0; r < 16; ++r) {
    accA0[r] = 0.f;
    accA1[r] = 0.f;
    accB0[r] = 0.f;
    accB1[r] = 0.f;
  }
  float lA = 0.f, lB = 0.f;

  gload16(kgA, smem[0] + ldsoff);
  gload16(kgB, smem[0] + 4096 + ldsoff);
  gload16(vgA, smem[0] + 8192 + ldsoff);
  gload16(vgB, smem[0] + 12288 + ldsoff);
  __syncthreads();

  int cur = 0;
  for (int kt = 0; kt < 16; ++kt) {
    if (kt < 15) {
      char* sn = smem[cur ^ 1];
      const size_t ko = (size_t)(kt + 1) * 4096;
      const int vo = (kt + 1) * 64;
      gload16(kgA + ko, sn + ldsoff);
      gload16(kgB + ko, sn + 4096 + ldsoff);
      gload16(vgA + vo, sn + 8192 + ldsoff);
      gload16(vgB + vo, sn + 12288 + ldsoff);
    }
    const char* kt_ = smem[cur];
    const char* vt_ = smem[cur] + 8192;

#pragma unroll
    for (int s = 0; s < 2; ++s) {
      const int kr = s * 32 + l31;
      short8 kf[4], vf[2][2];
#pragma unroll
      for (int ds = 0; ds < 4; ++ds)
        kf[ds] = *(const short8*)(kt_ + kr * 128 + (((2 * ds + hi) ^ (kr & 7)) << 4));
#pragma unroll
      for (int dt = 0; dt < 2; ++dt) {
        const int vr = dt * 32 + l31;
#pragma unroll
        for (int ks = 0; ks < 2; ++ks)
          vf[dt][ks] = *(const short8*)(
              vt_ + vr * 128 + (((s * 4 + ks * 2 + hi) ^ (vr & 7)) << 4));
      }

      f32x16 srA, srB;
#pragma unroll
      for (int r = 0; r < 16; ++r) {
        srA[r] = 0.f;
        srB[r] = 0.f;
      }
      __builtin_amdgcn_s_setprio(1);
      srA = MFMA32(kf[0], qfA[0], srA);
      srA = MFMA32(kf[1], qfA[1], srA);
      srA = MFMA32(kf[2], qfA[2], srA);
      srA = MFMA32(kf[3], qfA[3], srA);
      srB = MFMA32(kf[0], qfB[0], srB);
      srB = MFMA32(kf[1], qfB[1], srB);
      srB = MFMA32(kf[2], qfB[2], srB);
      srB = MFMA32(kf[3], qfB[3], srB);
      __builtin_amdgcn_s_setprio(0);

      float pA[16], pB[16];
#pragma unroll
      for (int r = 0; r < 16; ++r) pA[r] = fexp2(srA[r]);
#pragma unroll
      for (int r = 0; r < 16; ++r) pB[r] = fexp2(srB[r]);

      u32 a01 = cvtpk(pA[0], pA[1]), a23 = cvtpk(pA[2], pA[3]);
      u32 a45 = cvtpk(pA[4], pA[5]), a67 = cvtpk(pA[6], pA[7]);
      u32 a89 = cvtpk(pA[8], pA[9]), aab = cvtpk(pA[10], pA[11]);
      u32 acd = cvtpk(pA[12], pA[13]), aef = cvtpk(pA[14], pA[15]);
      u32x2 sa0 = __builtin_amdgcn_permlane32_swap(a01, a45, false, false);
      u32x2 sa1 = __builtin_amdgcn_permlane32_swap(a23, a67, false, false);
      u32x2 sa2 = __builtin_amdgcn_permlane32_swap(a89, acd, false, false);
      u32x2 sa3 = __builtin_amdgcn_permlane32_swap(aab, aef, false, false);
      S8U pfA0, pfA1;
      pfA0.u[0] = sa0[0];
      pfA0.u[1] = sa1[0];
      pfA0.u[2] = sa0[1];
      pfA0.u[3] = sa1[1];
      pfA1.u[0] = sa2[0];
      pfA1.u[1] = sa3[0];
      pfA1.u[2] = sa2[1];
      pfA1.u[3] = sa3[1];

      u32 b01 = cvtpk(pB[0], pB[1]), b23 = cvtpk(pB[2], pB[3]);
      u32 b45 = cvtpk(pB[4], pB[5]), b67 = cvtpk(pB[6], pB[7]);
      u32 b89 = cvtpk(pB[8], pB[9]), bab = cvtpk(pB[10], pB[11]);
      u32 bcd = cvtpk(pB[12], pB[13]), bef = cvtpk(pB[14], pB[15]);
      u32x2 sb0 = __builtin_amdgcn_permlane32_swap(b01, b45, false, false);
      u32x2 sb1 = __builtin_amdgcn_permlane32_swap(b23, b67, false, false);
      u32x2 sb2 = __builtin_amdgcn_permlane32_swap(b89, bcd, false, false);
      u32x2 sb3 = __builtin_amdgcn_permlane32_swap(bab, bef, false, false);
      S8U pfB0, pfB1;
      pfB0.u[0] = sb0[0];
      pfB0.u[1] = sb1[0];
      pfB0.u[2] = sb0[1];
      pfB0.u[3] = sb1[1];
      pfB1.u[0] = sb2[0];
      pfB1.u[1] = sb3[0];
      pfB1.u[2] = sb2[1];
      pfB1.u[3] = sb3[1];

      __builtin_amdgcn_s_setprio(1);
      accA0 = MFMA32(vf[0][0], pfA0.s, accA0);
      accA0 = MFMA32(vf[0][1], pfA1.s, accA0);
      accA1 = MFMA32(vf[1][0], pfA0.s, accA1);
      accA1 = MFMA32(vf[1][1], pfA1.s, accA1);
      accB0 = MFMA32(vf[0][0], pfB0.s, accB0);
      accB0 = MFMA32(vf[0][1], pfB1.s, accB0);
      accB1 = MFMA32(vf[1][0], pfB0.s, accB1);
      accB1 = MFMA32(vf[1][1], pfB1.s, accB1);
      __builtin_amdgcn_s_setprio(0);

      float psA = ((pA[0] + pA[1]) + (pA[2] + pA[3])) +
                  ((pA[4] + pA[5]) + (pA[6] + pA[7])) +
                  ((pA[8] + pA[9]) + (pA[10] + pA[11])) +
                  ((pA[12] + pA[13]) + (pA[14] + pA[15]));
      float psB = ((pB[0] + pB[1]) + (pB[2] + pB[3])) +
                  ((pB[4] + pB[5]) + (pB[6] + pB[7])) +
                  ((pB[8] + pB[9]) + (pB[10] + pB[11])) +
                  ((pB[12] + pB[13]) + (pB[14] + pB[15]));
      psA += __shfl_xor(psA, 32);
      psB += __shfl_xor(psB, 32);
      lA += psA;
      lB += psB;
    }
    __syncthreads();
    cur ^= 1;
  }

  const float invA = 1.f / lA, invB = 1.f / lB;
  bf16* obaseA = ob + ((size_t)(n * 1024 + q0 + l31) * 16 + h) * 64;
  bf16* obaseB = obaseA + (size_t)32 * 16 * 64;
#pragma unroll
  for (int dt = 0; dt < 2; ++dt) {
#pragma unroll
    for (int rb = 0; rb < 4; ++rb) {
      const int d0 = dt * 32 + rb * 8 + 4 * hi;
      const f32x16& aA = dt ? accA1 : accA0;
      const f32x16& aB = dt ? accB1 : accB0;
      u32x2 wA, wB;
      wA[0] = pk2(aA[4 * rb + 0] * invA, aA[4 * rb + 1] * invA);
      wA[1] = pk2(aA[4 * rb + 2] * invA, aA[4 * rb + 3] * invA);
      wB[0] = pk2(aB[4 * rb + 0] * invB, aB[4 * rb + 1] * invB);
      wB[1] = pk2(aB[4 * rb + 2] * invB, aB[4 * rb + 3] * invB);
      *(u32x2*)(obaseA + d0) = wA;
      *(u32x2*)(obaseB + d0) = wB;
    }
  }
}

// ---------------- output GEMM  out = A @ Wo^T + bo  (BK=64, XCD-swizzled) ----
__global__ __launch_bounds__(256) void out_gemm(const bf16* __restrict__ A,
                                                const bf16* __restrict__ B,
                                                const float* __restrict__ bias,
                                                float* __restrict__ out) {
  __shared__ __align__(16) char smem[2][32768];  // per buf: A 16KB | B 16KB
  const int t = threadIdx.x;
  const int lane = t & 63, wave = t >> 6;
  const int g = lane >> 4, c = lane & 15;
  const int wr = wave >> 1, wc = wave & 1;
  const int bid = blockIdx.x;                    // 0..511
  const int w = (bid & 7) * 64 + (bid >> 3);     // XCD-contiguous work id
  const int r0 = (w >> 3) * 128;                 // row tile (64 values)
  const int c0 = (w & 7) * 128;                  // col tile (8 values)

  const int sr8 = lane >> 3;
  const int scg = (lane & 7) ^ sr8;
  const int row0 = wave * 8 + sr8;
  const bf16* ag = A + (size_t)(r0 + row0) * 1024 + scg * 8;
  const bf16* bg = B + (size_t)(c0 + row0) * 1024 + scg * 8;
  const int ldsoff = wave * 1024;

  f32x4 acc[4][4];
#pragma unroll
  for (int ai = 0; ai < 4; ++ai)
#pragma unroll
    for (int bi = 0; bi < 4; ++bi) acc[ai][bi] = (f32x4){0.f, 0.f, 0.f, 0.f};

#pragma unroll
  for (int j = 0; j < 4; ++j) {
    gload16(ag + (size_t)j * 32 * 1024, smem[0] + j * 4096 + ldsoff);
    gload16(bg + (size_t)j * 32 * 1024, smem[0] + 16384 + j * 4096 + ldsoff);
  }
  __syncthreads();

  int cur = 0;
  for (int kt = 0; kt < 16; ++kt) {
    if (kt < 15) {
      char* sn = smem[cur ^ 1];
      const int k1 = (kt + 1) * 64;
#pragma unroll
      for (int j = 0; j < 4; ++j) {
        gload16(ag + (size_t)j * 32 * 1024 + k1, sn + j * 4096 + ldsoff);
        gload16(bg + (size_t)j * 32 * 1024 + k1, sn + 16384 + j * 4096 + ldsoff);
      }
    }
    const char* sa = smem[cur];
    const char* sb = smem[cur] + 16384;

#pragma unroll
    for (int h2 = 0; h2 < 2; ++h2) {
      short8 af[4], bfr[4];
#pragma unroll
      for (int ai = 0; ai < 4; ++ai) {
        const int row = wr * 64 + ai * 16 + c;
        af[ai] = *(const short8*)(sa + row * 128 + (((h2 * 4 + g) ^ (row & 7)) << 4));
      }
#pragma unroll
      for (int bi = 0; bi < 4; ++bi) {
        const int row = wc * 64 + bi * 16 + c;
        bfr[bi] = *(const short8*)(sb + row * 128 + (((h2 * 4 + g) ^ (row & 7)) << 4));
      }
      __builtin_amdgcn_s_setprio(1);
#pragma unroll
      for (int ai = 0; ai < 4; ++ai)
#pragma unroll
        for (int bi = 0; bi < 4; ++bi) acc[ai][bi] = MFMA16(af[ai], bfr[bi], acc[ai][bi]);
      __builtin_amdgcn_s_setprio(0);
    }

    __syncthreads();
    cur ^= 1;
  }

#pragma unroll
  for (int bi = 0; bi < 4; ++bi) {
    const int e = c0 + wc * 64 + bi * 16 + c;
    const float bv = bias[e];
#pragma unroll
    for (int ai = 0; ai < 4; ++ai) {
#pragma unroll
      for (int i = 0; i < 4; ++i) {
        out[(size_t)(r0 + wr * 64 + ai * 16 + 4 * g + i) * 1024 + e] =
            acc[ai][bi][i] + bv;
      }
    }
  }
}

extern "C" void kernel_launch(void* const* d_in, const int* in_sizes, int n_in,
                              void* d_out, int out_size, void* d_ws, size_t ws_size,
                              hipStream_t stream) {
  const float* values = (const float*)d_in[0];
  const float* keys = (const float*)d_in[1];
  const float* query = (const float*)d_in[2];
  const float* position = (const float*)d_in[3];
  const float* Wv = (const float*)d_in[4];
  const float* Wk = (const float*)d_in[5];
  const float* Wq = (const float*)d_in[6];
  const float* Wpos = (const float*)d_in[7];
  const float* Wo = (const float*)d_in[8];
  const float* bo = (const float*)d_in[9];

  char* ws = (char*)d_ws;
  bf16* qb = (bf16*)(ws);                          // 16MB
  bf16* kb = (bf16*)(ws + ((size_t)16 << 20));     // 16MB
  bf16* vT = (bf16*)(ws + ((size_t)32 << 20));     // 16MB
  bf16* posb = (bf16*)(ws + ((size_t)48 << 20));   // 4MB [8192][256]
  bf16* ob = (bf16*)(ws + ((size_t)52 << 20));     // 16MB
  bf16* wo16 = (bf16*)(ws + ((size_t)68 << 20));   // 2MB
  float* out = (float*)d_out;

  fused_pre<<<2688, 256, 0, stream>>>(position, Wpos, keys, Wk, values, Wv, Wo,
                                      posb, kb, vT, wo16);
  q_gemm<<<dim3(64, 16), 256, 0, stream>>>(query, posb, Wq, qb);
  attn_kernel<<<512, 256, 0, stream>>>(qb, kb, vT, ob);
  out_gemm<<<512, 256, 0, stream>>>(ob, wo16, bo, out);
}